// Round 9
// baseline (175.073 us; speedup 1.0000x reference)
//
#include <hip/hip_runtime.h>
#include <hip/hip_fp8.h>

typedef unsigned short u16;
typedef unsigned char  u8;
typedef __bf16 bf16x4 __attribute__((ext_vector_type(4)));
typedef __bf16 bf16x8 __attribute__((ext_vector_type(8)));
typedef float  f32x4  __attribute__((ext_vector_type(4)));
typedef float  f32x16 __attribute__((ext_vector_type(16)));

#define MFMA16(a, b, c)   __builtin_amdgcn_mfma_f32_16x16x32_bf16((a), (b), (c), 0, 0, 0)
#define MFMA32(a, b, c)   __builtin_amdgcn_mfma_f32_32x32x16_bf16((a), (b), (c), 0, 0, 0)
#define MFMA32F8(a, b, c) __builtin_amdgcn_mfma_f32_32x32x16_fp8_fp8((a), (b), (c), 0, 0, 0)

__device__ inline u8 to_e4m3(float f) {
    return (u8)__hip_cvt_float_to_fp8(f, __HIP_SATFINITE, __HIP_E4M3);
}

// ---------------------------------------------------------------------------
// Geometry: N=2, L=2048, E=1024, H=16, D=64.
// R9: hybrid fp8. Q,K stored fp8 e4m3 (each carries sqrt(log2e/sqrt(E)));
// conversion via hip_fp8.h API (R8's hand-packed cvt builtin produced NaN —
// scrambled Q/K bytes amplified through exp2 to inf -> 0*inf).  V and P stay
// bf16: flash PV half is byte-identical to the proven R7 kernel.  S-tile uses
// fp8 MFMA (K staged int2, Q frags long from global).  Combine stays fused
// into out_gemm A-staging.
// ---------------------------------------------------------------------------

// Kernel 1: fused {Wo f32->bf16 convert | shared projection}.
// Blocks 0..3071: y = x @ Wv^T + bv (t=0 values->VT bf16, 1 keys fp8, 2 query fp8).
// Blocks 3072..4095: Wo convert (bf16).
__global__ __launch_bounds__(256) void prep_kernel(
    const float* __restrict__ values, const float* __restrict__ keys,
    const float* __restrict__ query,  const float* __restrict__ Wv,
    const float* __restrict__ bv,     const float* __restrict__ Wo,
    u8* __restrict__ Qb, u8* __restrict__ Kb, u16* __restrict__ VTb,
    u16* __restrict__ Wob) {
    const int b = blockIdx.x;
    const int t = b >> 10;
    if (t == 3) {  // Wo convert
        const int i = ((b - 3072) * 256 + threadIdx.x) * 4;
        float4 v = *(const float4*)&Wo[i];
        bf16x4 o = { (__bf16)v.x, (__bf16)v.y, (__bf16)v.z, (__bf16)v.w };
        *(bf16x4*)&Wob[i] = o;
        return;
    }
    __shared__ __align__(16) u16 Wvs[64 * 72];
    __shared__ __align__(16) u16 Xs[64 * 72];
    u8* Xs8 = (u8*)Xs;  // fp8 staging view (rows pitch 72 B) for t=1,2
    const int lt = b & 31, h = (b >> 5) & 15, n = (b >> 9) & 1;
    const int nh = n * 16 + h, l0 = lt * 64;
    const int tid = threadIdx.x, wave = tid >> 6, lane = tid & 63;
    const int quad = lane >> 4, l16 = lane & 15;
    const float* xin = (t == 0) ? values : (t == 1 ? keys : query);

#pragma unroll
    for (int j = 0; j < 4; ++j) {
        const int chunk = tid + 256 * j, r = chunk >> 4, c = (chunk & 15) * 4;
        float4 w = *(const float4*)&Wv[r * 64 + c];
        bf16x4 wb = { (__bf16)w.x, (__bf16)w.y, (__bf16)w.z, (__bf16)w.w };
        *(bf16x4*)&Wvs[r * 72 + c] = wb;
        float4 x = *(const float4*)&xin[(size_t)(n * 2048 + l0 + r) * 1024 + h * 64 + c];
        bf16x4 xb = { (__bf16)x.x, (__bf16)x.y, (__bf16)x.z, (__bf16)x.w };
        *(bf16x4*)&Xs[r * 72 + c] = xb;
    }
    __syncthreads();

    bf16x8 wf[4][2], xf[2];
#pragma unroll
    for (int f = 0; f < 4; ++f)
#pragma unroll
        for (int ks = 0; ks < 2; ++ks)
            wf[f][ks] = *(const bf16x8*)&Wvs[(f * 16 + l16) * 72 + ks * 32 + quad * 8];
#pragma unroll
    for (int ks = 0; ks < 2; ++ks)
        xf[ks] = *(const bf16x8*)&Xs[(wave * 16 + l16) * 72 + ks * 32 + quad * 8];

    f32x4 acc[4];
#pragma unroll
    for (int i = 0; i < 4; ++i) acc[i] = (f32x4){0.f, 0.f, 0.f, 0.f};

    if (t == 0) {  // V: y = x·Wv^T
#pragma unroll
        for (int nf = 0; nf < 4; ++nf) {
            acc[nf] = MFMA16(xf[0], wf[nf][0], acc[nf]);
            acc[nf] = MFMA16(xf[1], wf[nf][1], acc[nf]);
        }
    } else {       // Q/K: y^T = Wv·x^T
#pragma unroll
        for (int mf = 0; mf < 4; ++mf) {
            acc[mf] = MFMA16(wf[mf][0], xf[0], acc[mf]);
            acc[mf] = MFMA16(wf[mf][1], xf[1], acc[mf]);
        }
    }
    __syncthreads();

    const float scale = 0.2123305f;  // sqrt(log2(e)/sqrt(1024)) on Q AND K
    if (t == 0) {
        // bf16 V: D[l=wave*16+quad*4+r][e=nf*16+l16] -> VT[d=e][l]
#pragma unroll
        for (int nf = 0; nf < 4; ++nf) {
            const float bias = bv[nf * 16 + l16];
            bf16x4 o = { (__bf16)(acc[nf][0] + bias), (__bf16)(acc[nf][1] + bias),
                         (__bf16)(acc[nf][2] + bias), (__bf16)(acc[nf][3] + bias) };
            *(bf16x4*)&Xs[(nf * 16 + l16) * 72 + wave * 16 + quad * 4] = o;
        }
    } else {
        // fp8 Q/K: D[e=mf*16+quad*4+r][l=wave*16+l16] -> [l][e]
#pragma unroll
        for (int mf = 0; mf < 4; ++mf) {
            const u8 b0 = to_e4m3((acc[mf][0] + bv[mf * 16 + quad * 4 + 0]) * scale);
            const u8 b1 = to_e4m3((acc[mf][1] + bv[mf * 16 + quad * 4 + 1]) * scale);
            const u8 b2 = to_e4m3((acc[mf][2] + bv[mf * 16 + quad * 4 + 2]) * scale);
            const u8 b3 = to_e4m3((acc[mf][3] + bv[mf * 16 + quad * 4 + 3]) * scale);
            const int pk = (int)b0 | ((int)b1 << 8) | ((int)b2 << 16) | ((int)b3 << 24);
            *(int*)&Xs8[(wave * 16 + l16) * 72 + mf * 16 + quad * 4] = pk;
        }
    }
    __syncthreads();

    if (t == 0) {
#pragma unroll
        for (int j = 0; j < 2; ++j) {
            const int chunk = tid + 256 * j, r = chunk >> 3, c = (chunk & 7) * 8;
            *(int4*)&VTb[(size_t)(nh * 64 + r) * 2048 + l0 + c] = *(const int4*)&Xs[r * 72 + c];
        }
    } else {
        u8* dst = (t == 1) ? Kb : Qb;
#pragma unroll
        for (int j = 0; j < 2; ++j) {
            const int chunk = tid + 256 * j, r = chunk >> 3, c = (chunk & 7) * 8;
            *(int2*)&dst[(size_t)(nh * 2048 + l0 + r) * 64 + c] = *(const int2*)&Xs8[r * 72 + c];
        }
    }
}

// Kernel 2: attention partials. S-tile: fp8 MFMA (K fp8 LDS, Q fp8 global);
// softmax P -> bf16; PV: bf16 MFMA (byte-identical to proven R7 path).
// Split-K x2; block = 4 waves x 32 q; grid = 32 nh x 16 qslab x 2 ks.
// S^T C-layout: col=q=lane&31, row=key=(reg&3)+8*(reg>>2)+4*(lane>>5).
// Epilogue: fold per-q l (shfl_xor 32); transpose O via Pw; bf16 partials
// in AO layout (Op[ks] = [4096][1024]) + Lp.
__global__ __launch_bounds__(256, 4) void flash_kernel(
    const u8* __restrict__ Qb, const u8* __restrict__ Kb,
    const u16* __restrict__ VTb, u16* __restrict__ Op,
    float* __restrict__ Lp) {
    __shared__ __align__(16) u8  Ks[64 * 72];      // fp8 K tile
    __shared__ __align__(16) u16 Vs[64 * 72];      // bf16 V tile
    __shared__ __align__(16) u16 Ps[4][32 * 72];   // bf16 wave-private P
    const int b = blockIdx.x;
    const int nh = b >> 5, qsl = (b >> 1) & 15, ks = b & 1;
    const int tid = threadIdx.x, wave = tid >> 6, lane = tid & 63;
    const int l32 = lane & 31, half = lane >> 5;
    const int q0 = qsl * 128 + wave * 32;
    const int s4 = (b >> 1) * 4 + wave;  // (nh*16+qsl)*4 + wave
    u16* Pw = &Ps[wave][0];

    // Q B-frags direct from global (fp8): B[kd=kg*16+half*8+j][q=l32].
    const u8* Qg = Qb + ((size_t)nh * 2048 + q0) * 64;
    long qf[4];
#pragma unroll
    for (int kg = 0; kg < 4; ++kg)
        qf[kg] = *(const long*)&Qg[l32 * 64 + kg * 16 + half * 8];

    f32x16 Oacc[2];
#pragma unroll
    for (int dt = 0; dt < 2; ++dt)
#pragma unroll
        for (int r = 0; r < 16; ++r) Oacc[dt][r] = 0.f;
    float lsum = 0.f;

    const u8*  Kg = Kb + (size_t)nh * 2048 * 64;
    const u16* Vg = VTb + (size_t)nh * 64 * 2048;

    for (int kt = 0; kt < 16; ++kt) {
        __syncthreads();  // prior tile's Ks/Vs reads complete
        const int k0 = ks * 1024 + kt * 64;
#pragma unroll
        for (int j = 0; j < 2; ++j) {
            const int chunk = tid + 256 * j, r = chunk >> 3, c = (chunk & 7) * 8;
            *(int2*)&Ks[r * 72 + c] = *(const int2*)&Kg[(size_t)(k0 + r) * 64 + c];
            *(int4*)&Vs[r * 72 + c] = *(const int4*)&Vg[(size_t)r * 2048 + k0 + c];
        }
        __syncthreads();

        // Two 32-key S^T tiles: s = K(32 x d64) · Q^T(d64 x 32q), fp8 MFMA.
#pragma unroll
        for (int t2 = 0; t2 < 2; ++t2) {
            f32x16 s;
#pragma unroll
            for (int r = 0; r < 16; ++r) s[r] = 0.f;
#pragma unroll
            for (int kg = 0; kg < 4; ++kg) {
                long ak = *(const long*)&Ks[(t2 * 32 + l32) * 72 + kg * 16 + half * 8];
                s = MFMA32F8(ak, qf[kg], s);
            }
            // exp2, per-lane partial row sums, pack bf16 P -> b64 writes.
            // reg r=4a+bb holds key = bb + 8a + 4*half (+32*t2), q = l32.
#pragma unroll
            for (int a = 0; a < 4; ++a) {
                const float p0 = __builtin_amdgcn_exp2f(s[4 * a + 0]);
                const float p1 = __builtin_amdgcn_exp2f(s[4 * a + 1]);
                const float p2 = __builtin_amdgcn_exp2f(s[4 * a + 2]);
                const float p3 = __builtin_amdgcn_exp2f(s[4 * a + 3]);
                lsum += (p0 + p1) + (p2 + p3);
                bf16x4 pk = { (__bf16)p0, (__bf16)p1, (__bf16)p2, (__bf16)p3 };
                *(bf16x4*)&Pw[l32 * 72 + t2 * 32 + a * 8 + half * 4] = pk;
            }
        }

        // O^T += V^T·P^T (bf16): A[m=d=dt*32+l32][k=key], B[k=key][q=l32]
#pragma unroll
        for (int kk = 0; kk < 4; ++kk) {
            bf16x8 bp = *(const bf16x8*)&Pw[l32 * 72 + kk * 16 + half * 8];
#pragma unroll
            for (int dt = 0; dt < 2; ++dt) {
                bf16x8 av = *(const bf16x8*)&Vs[(dt * 32 + l32) * 72 + kk * 16 + half * 8];
                Oacc[dt] = MFMA32(av, bp, Oacc[dt]);
            }
        }
    }

    // Fold the two key-halves of this lane's partial row sum -> l(q) per ks.
    const float lq = lsum + __shfl_xor(lsum, 32);
    if (half == 0)
        Lp[((size_t)s4 * 2 + ks) * 32 + l32] = lq;

    // Transpose O^T (col=q=l32, row=d=(r&3)+8*(r>>2)+4*half+32*dt) into
    // O[q][d] via Pw, then coalesced b128 stores of bf16 partials (AO layout).
#pragma unroll
    for (int dt = 0; dt < 2; ++dt)
#pragma unroll
        for (int a = 0; a < 4; ++a) {
            bf16x4 o = { (__bf16)Oacc[dt][4 * a + 0], (__bf16)Oacc[dt][4 * a + 1],
                         (__bf16)Oacc[dt][4 * a + 2], (__bf16)Oacc[dt][4 * a + 3] };
            *(bf16x4*)&Pw[l32 * 72 + dt * 32 + a * 8 + half * 4] = o;
        }
    u16* Ob = Op + (size_t)ks * 4194304 +
              ((size_t)(nh >> 4) * 2048 + q0) * 1024 + (nh & 15) * 64;
#pragma unroll
    for (int j = 0; j < 4; ++j) {
        const int chunk = lane + 64 * j, r = chunk >> 3, c = (chunk & 7) * 8;
        *(int4*)&Ob[(size_t)r * 1024 + c] = *(const int4*)&Pw[r * 72 + c];
    }
}

// Kernel 3: out = ((O1+O2)*inv_l) @ Wo^T + bo, f32 out. Combine fused into
// A-staging (per kt the 64-wide k-block is head h=kt -> one l(row,h) lookup
// per staged row). 512 thr, 128x64 tile, 8 waves of 32x32 (MFMA32 bf16).
__global__ __launch_bounds__(512) void out_gemm_kernel(
    const u16* __restrict__ Op, const float* __restrict__ Lp,
    const u16* __restrict__ Bw, const float* __restrict__ bo,
    float* __restrict__ out) {
    __shared__ __align__(16) u16 As[128 * 72];
    __shared__ __align__(16) u16 Bs[64 * 72];
    const int b = blockIdx.x, rt = b >> 4, ct = b & 15;
    const int row0 = rt * 128, col0 = ct * 64;
    const int n16 = (rt >> 4) * 16, qsl = rt & 15;
    const int tid = threadIdx.x, wave = tid >> 6, lane = tid & 63;
    const int l32 = lane & 31, half = lane >> 5;
    const int wr = wave & 3, wc = wave >> 2;

    f32x16 acc;
#pragma unroll
    for (int r = 0; r < 16; ++r) acc[r] = 0.f;

    for (int kt = 0; kt < 16; ++kt) {
        __syncthreads();
        const int k0 = kt * 64;
        const int s4h = ((n16 + kt) * 16 + qsl) * 4;  // s4 base for this head
#pragma unroll
        for (int j = 0; j < 2; ++j) {
            const int chunk = tid + 512 * j, r = chunk >> 3, c = (chunk & 7) * 8;
            const int w = r >> 5, q = r & 31;
            const float l = Lp[(size_t)(s4h + w) * 64 + q] +
                            Lp[(size_t)(s4h + w) * 64 + 32 + q];
            const float inv = 1.0f / l;
            const size_t off = (size_t)(row0 + r) * 1024 + k0 + c;
            bf16x8 a = *(const bf16x8*)&Op[off];
            bf16x8 c8 = *(const bf16x8*)&Op[4194304 + off];
            bf16x8 o;
#pragma unroll
            for (int i = 0; i < 8; ++i)
                o[i] = (__bf16)(((float)a[i] + (float)c8[i]) * inv);
            *(bf16x8*)&As[r * 72 + c] = o;
        }
        {
            const int r = tid >> 3, c = (tid & 7) * 8;
            *(int4*)&Bs[r * 72 + c] = *(const int4*)&Bw[(size_t)(col0 + r) * 1024 + k0 + c];
        }
        __syncthreads();
#pragma unroll
        for (int kg = 0; kg < 4; ++kg) {
            bf16x8 af = *(const bf16x8*)&As[(wr * 32 + l32) * 72 + kg * 16 + half * 8];
            bf16x8 bf = *(const bf16x8*)&Bs[(wc * 32 + l32) * 72 + kg * 16 + half * 8];
            acc = MFMA32(af, bf, acc);
        }
    }

    // C layout: col = l32 (local), row = (r&3)+8*(r>>2)+4*half (local).
    const int col = col0 + wc * 32 + l32;
    const float bias = bo[col];
#pragma unroll
    for (int r = 0; r < 16; ++r) {
        const int row = row0 + wr * 32 + (r & 3) + 8 * (r >> 2) + 4 * half;
        out[(size_t)row * 1024 + col] = acc[r] + bias;
    }
}

extern "C" void kernel_launch(void* const* d_in, const int* in_sizes, int n_in,
                              void* d_out, int out_size, void* d_ws, size_t ws_size,
                              hipStream_t stream) {
    (void)in_sizes; (void)n_in; (void)out_size; (void)ws_size;
    const float* values = (const float*)d_in[0];
    const float* keys   = (const float*)d_in[1];
    const float* query  = (const float*)d_in[2];
    const float* Wv     = (const float*)d_in[3];
    const float* bv     = (const float*)d_in[4];
    const float* Wo     = (const float*)d_in[5];
    const float* bo     = (const float*)d_in[6];

    char* ws = (char*)d_ws;
    u8*    Qb  = (u8*)(ws);                      // [32][2048][64] fp8, 4 MB
    u8*    Kb  = (u8*)(ws + (4ull  << 20));      // [32][2048][64] fp8, 4 MB
    u16*   VTb = (u16*)(ws + (8ull  << 20));     // [32][64][2048] bf16, 8 MB
    u16*   Wob = (u16*)(ws + (16ull << 20));     // [1024][1024]  bf16, 2 MB
    u16*   Op  = (u16*)(ws + (18ull << 20));     // 2 x [4096][1024] bf16, 16 MB
    float* Lp  = (float*)(ws + (34ull << 20));   // [2048][2][32] f32, 512 KB

    prep_kernel<<<4096, 256, 0, stream>>>(values, keys, query, Wv, bv, Wo,
                                          Qb, Kb, VTb, Wob);
    flash_kernel<<<1024, 256, 0, stream>>>(Qb, Kb, VTb, Op, Lp);
    out_gemm_kernel<<<512, 512, 0, stream>>>(Op, Lp, Wob, bo, (float*)d_out);
}